// Round 1
// baseline (195.215 us; speedup 1.0000x reference)
//
#include <hip/hip_runtime.h>
#include <math.h>

#define Bn 2
#define Kn 8
#define Cn 256
#define HWn (128*128)
#define Sn 2048
#define TS 64
#define CHUNK 64
#define PAD 68   // LDS row stride in floats: 272B, 16B-aligned, bank-rotates by 4/row

__global__ __launch_bounds__(64) void zero_accum_kernel(float* __restrict__ accum) {
    if (threadIdx.x < 2) accum[threadIdx.x] = 0.0f;
}

// One block per (b,s): gather feature column at idx, L2-normalize over C,
// write transposed row fT[b*S+s][c]; threads 0..7 also gather+sigmoid masks.
__global__ __launch_bounds__(256) void gather_kernel(
    const float* __restrict__ masks, const float* __restrict__ feats,
    const int* __restrict__ indices, float* __restrict__ fT, float* __restrict__ mS)
{
    const int bs = blockIdx.x;
    const int b  = bs >> 11;        // / Sn
    const int s  = bs & (Sn - 1);
    const int c  = threadIdx.x;     // 0..255 == Cn
    const int id = indices[b * Sn + s];

    const float v = feats[((size_t)(b * Cn + c)) * HWn + id];

    // block reduction of v*v (4 waves of 64)
    float x = v * v;
    #pragma unroll
    for (int o = 32; o > 0; o >>= 1) x += __shfl_down(x, o);
    __shared__ float part[4];
    if ((threadIdx.x & 63) == 0) part[threadIdx.x >> 6] = x;
    __syncthreads();
    const float total = part[0] + part[1] + part[2] + part[3];
    const float scale = 1.0f / fmaxf(sqrtf(total), 1e-12f);

    fT[(size_t)bs * Cn + c] = v * scale;

    if (c < Kn) {
        const float lg = masks[((size_t)(b * Kn + c)) * HWn + id];
        mS[(size_t)bs * Kn + c] = 1.0f / (1.0f + expf(-lg));
    }
}

// 64x64 tile of sim per block; 16x16 threads, 4x4 register tile each.
// C looped in chunks of 64 through padded LDS. Threshold + m-diff fused.
__global__ __launch_bounds__(256) void sim_kernel(
    const float* __restrict__ fT, const float* __restrict__ mS,
    float* __restrict__ accum)
{
    __shared__ float As[TS * PAD];
    __shared__ float Bs[TS * PAD];
    __shared__ float mA[TS * Kn];
    __shared__ float mB[TS * Kn];
    __shared__ float rn[4], rd[4];

    const int b  = blockIdx.z;
    const int s0 = blockIdx.y * TS;
    const int t0 = blockIdx.x * TS;
    const int tid = threadIdx.x;
    const int tx = tid & 15;        // t-dim
    const int ty = tid >> 4;        // s-dim (0..15)

    // stage m tiles (512 floats each, contiguous)
    for (int q = tid; q < TS * Kn; q += 256) {
        mA[q] = mS[((size_t)(b * Sn + s0)) * Kn + q];
        mB[q] = mS[((size_t)(b * Sn + t0)) * Kn + q];
    }

    const float* Abase = fT + ((size_t)(b * Sn + s0)) * Cn;
    const float* Bbase = fT + ((size_t)(b * Sn + t0)) * Cn;

    float acc[4][4];
    #pragma unroll
    for (int i = 0; i < 4; ++i)
        #pragma unroll
        for (int j = 0; j < 4; ++j) acc[i][j] = 0.0f;

    for (int c0 = 0; c0 < Cn; c0 += CHUNK) {
        __syncthreads();   // previous chunk fully consumed (also orders mA/mB writes)
        #pragma unroll
        for (int p = 0; p < 4; ++p) {
            const int r  = (tid >> 4) + 16 * p;   // 0..63
            const int c4 = (tid & 15) * 4;        // 0..60
            *(float4*)(&As[r * PAD + c4]) =
                *(const float4*)(Abase + (size_t)r * Cn + c0 + c4);
            *(float4*)(&Bs[r * PAD + c4]) =
                *(const float4*)(Bbase + (size_t)r * Cn + c0 + c4);
        }
        __syncthreads();
        #pragma unroll
        for (int cc = 0; cc < CHUNK; cc += 4) {
            float4 av[4], bv[4];
            #pragma unroll
            for (int i = 0; i < 4; ++i)
                av[i] = *(const float4*)(&As[(ty + 16 * i) * PAD + cc]);
            #pragma unroll
            for (int j = 0; j < 4; ++j)
                bv[j] = *(const float4*)(&Bs[(tx + 16 * j) * PAD + cc]);
            #pragma unroll
            for (int i = 0; i < 4; ++i)
                #pragma unroll
                for (int j = 0; j < 4; ++j)
                    acc[i][j] += av[i].x * bv[j].x + av[i].y * bv[j].y
                               + av[i].z * bv[j].z + av[i].w * bv[j].w;
        }
    }

    // threshold + masked m-diff accumulation (branch is ~never taken off-diagonal)
    float num_l = 0.0f, den_l = 0.0f;
    #pragma unroll
    for (int i = 0; i < 4; ++i) {
        #pragma unroll
        for (int j = 0; j < 4; ++j) {
            if (acc[i][j] > 0.95f) {
                den_l += 1.0f;
                const float* ma = &mA[(ty + 16 * i) * Kn];
                const float* mb = &mB[(tx + 16 * j) * Kn];
                #pragma unroll
                for (int k = 0; k < Kn; ++k) num_l += fabsf(ma[k] - mb[k]);
            }
        }
    }

    #pragma unroll
    for (int o = 32; o > 0; o >>= 1) {
        num_l += __shfl_down(num_l, o);
        den_l += __shfl_down(den_l, o);
    }
    if ((tid & 63) == 0) { rn[tid >> 6] = num_l; rd[tid >> 6] = den_l; }
    __syncthreads();
    if (tid == 0) {
        atomicAdd(&accum[0], rn[0] + rn[1] + rn[2] + rn[3]);
        atomicAdd(&accum[1], rd[0] + rd[1] + rd[2] + rd[3]);
    }
}

__global__ __launch_bounds__(64) void finalize_kernel(
    const float* __restrict__ accum, float* __restrict__ out)
{
    if (threadIdx.x == 0) out[0] = accum[0] / (accum[1] + 1e-6f);
}

extern "C" void kernel_launch(void* const* d_in, const int* in_sizes, int n_in,
                              void* d_out, int out_size, void* d_ws, size_t ws_size,
                              hipStream_t stream) {
    const float* masks   = (const float*)d_in[0];   // (B,K,H,W) fp32
    const float* feats   = (const float*)d_in[1];   // (B,C,H,W) fp32
    const int*   indices = (const int*)d_in[2];     // (B,S) int32
    float* out = (float*)d_out;

    float* ws   = (float*)d_ws;
    float* fT   = ws;                                  // B*S*C floats (4 MB)
    float* mSm  = ws + (size_t)Bn * Sn * Cn;           // B*S*K floats
    float* accum = mSm + (size_t)Bn * Sn * Kn;         // 2 floats

    zero_accum_kernel<<<1, 64, 0, stream>>>(accum);
    gather_kernel<<<Bn * Sn, 256, 0, stream>>>(masks, feats, indices, fT, mSm);
    dim3 grid(Sn / TS, Sn / TS, Bn);
    sim_kernel<<<grid, 256, 0, stream>>>(fT, mSm, accum);
    finalize_kernel<<<1, 64, 0, stream>>>(accum, out);
}

// Round 2
// 58.080 us; speedup vs baseline: 3.3611x; 3.3611x over previous
//
#include <hip/hip_runtime.h>
#include <hip/hip_bf16.h>
#include <math.h>

#define Bn 2
#define Kn 8
#define Cn 256
#define HWn (128*128)
#define Sn 2048
#define BT 128   // block output tile (2x2 waves of 64x64)

typedef __bf16 bf16x8 __attribute__((ext_vector_type(8)));
typedef float  f32x4  __attribute__((ext_vector_type(4)));

__global__ __launch_bounds__(64) void zero_accum_kernel(float* __restrict__ accum) {
    if (threadIdx.x < 2) accum[threadIdx.x] = 0.0f;
}

// One block per (b,s): gather feature column at idx, L2-normalize over C,
// write bf16 transposed row fTb[b*S+s][c]; threads 0..7 gather+sigmoid masks.
__global__ __launch_bounds__(256) void gather_kernel(
    const float* __restrict__ masks, const float* __restrict__ feats,
    const int* __restrict__ indices, ushort* __restrict__ fTb,
    float* __restrict__ mS)
{
    const int bs = blockIdx.x;
    const int b  = bs >> 11;        // / Sn
    const int s  = bs & (Sn - 1);
    const int c  = threadIdx.x;     // 0..255 == Cn
    const int id = indices[b * Sn + s];

    const float v = feats[((size_t)(b * Cn + c)) * HWn + id];

    float x = v * v;
    #pragma unroll
    for (int o = 32; o > 0; o >>= 1) x += __shfl_down(x, o);
    __shared__ float part[4];
    if ((threadIdx.x & 63) == 0) part[threadIdx.x >> 6] = x;
    __syncthreads();
    const float total = part[0] + part[1] + part[2] + part[3];
    const float scale = 1.0f / fmaxf(sqrtf(total), 1e-12f);

    __hip_bfloat16 hv = __float2bfloat16(v * scale);
    fTb[(size_t)bs * Cn + c] = *reinterpret_cast<const ushort*>(&hv);

    if (c < Kn) {
        const float lg = masks[((size_t)(b * Kn + c)) * HWn + id];
        mS[(size_t)bs * Kn + c] = 1.0f / (1.0f + expf(-lg));
    }
}

// MFMA Gram matrix, fragments loaded straight from global (L2-resident, 2 MB).
// Block = 256 threads = 4 waves in 2x2; each wave owns a 64x64 output tile
// (4x4 fragments of 16x16x32 bf16). Threshold + m-diff fused in epilogue.
__global__ __launch_bounds__(256, 2) void sim_kernel(
    const ushort* __restrict__ fTb, const float* __restrict__ mS,
    float* __restrict__ accum)
{
    const int b   = blockIdx.z;
    const int s0  = blockIdx.y * BT;
    const int t0  = blockIdx.x * BT;
    const int tid = threadIdx.x;
    const int lane = tid & 63;
    const int wave = tid >> 6;
    const int wm = wave >> 1, wn = wave & 1;
    const int l15 = lane & 15, l4 = lane >> 4;

    const ushort* F = fTb + (size_t)b * Sn * Cn;
    // A frag m: row s0+wm*64+m*16+l15, k chunk l4*8
    const ushort* pA = F + (size_t)(s0 + wm * 64 + l15) * Cn + l4 * 8;
    const ushort* pB = F + (size_t)(t0 + wn * 64 + l15) * Cn + l4 * 8;

    f32x4 acc[4][4];
    #pragma unroll
    for (int m = 0; m < 4; ++m)
        #pragma unroll
        for (int n = 0; n < 4; ++n) acc[m][n] = (f32x4){0.f, 0.f, 0.f, 0.f};

    #pragma unroll
    for (int k0 = 0; k0 < Cn; k0 += 32) {
        bf16x8 aF[4], bF[4];
        #pragma unroll
        for (int m = 0; m < 4; ++m)
            aF[m] = *reinterpret_cast<const bf16x8*>(pA + (size_t)m * 16 * Cn + k0);
        #pragma unroll
        for (int n = 0; n < 4; ++n)
            bF[n] = *reinterpret_cast<const bf16x8*>(pB + (size_t)n * 16 * Cn + k0);
        #pragma unroll
        for (int m = 0; m < 4; ++m)
            #pragma unroll
            for (int n = 0; n < 4; ++n)
                acc[m][n] = __builtin_amdgcn_mfma_f32_16x16x32_bf16(
                    aF[m], bF[n], acc[m][n], 0, 0, 0);
    }

    // C/D layout: col = lane&15, row = (lane>>4)*4 + reg  [HW-verified m89]
    float num_l = 0.0f, den_l = 0.0f;
    const float* mSb = mS + (size_t)b * Sn * Kn;
    #pragma unroll
    for (int m = 0; m < 4; ++m) {
        #pragma unroll
        for (int n = 0; n < 4; ++n) {
            #pragma unroll
            for (int r = 0; r < 4; ++r) {
                if (acc[m][n][r] > 0.95f) {
                    den_l += 1.0f;
                    const int srow = s0 + wm * 64 + m * 16 + l4 * 4 + r;
                    const int tcol = t0 + wn * 64 + n * 16 + l15;
                    const float* ma = mSb + (size_t)srow * Kn;
                    const float* mb = mSb + (size_t)tcol * Kn;
                    #pragma unroll
                    for (int k = 0; k < Kn; ++k) num_l += fabsf(ma[k] - mb[k]);
                }
            }
        }
    }

    #pragma unroll
    for (int o = 32; o > 0; o >>= 1) {
        num_l += __shfl_down(num_l, o);
        den_l += __shfl_down(den_l, o);
    }
    __shared__ float rn[4], rd[4];
    if (lane == 0) { rn[wave] = num_l; rd[wave] = den_l; }
    __syncthreads();
    if (tid == 0) {
        atomicAdd(&accum[0], rn[0] + rn[1] + rn[2] + rn[3]);
        atomicAdd(&accum[1], rd[0] + rd[1] + rd[2] + rd[3]);
    }
}

__global__ __launch_bounds__(64) void finalize_kernel(
    const float* __restrict__ accum, float* __restrict__ out)
{
    if (threadIdx.x == 0) out[0] = accum[0] / (accum[1] + 1e-6f);
}

extern "C" void kernel_launch(void* const* d_in, const int* in_sizes, int n_in,
                              void* d_out, int out_size, void* d_ws, size_t ws_size,
                              hipStream_t stream) {
    const float* masks   = (const float*)d_in[0];   // (B,K,H,W) fp32
    const float* feats   = (const float*)d_in[1];   // (B,C,H,W) fp32
    const int*   indices = (const int*)d_in[2];     // (B,S) int32
    float* out = (float*)d_out;

    // ws layout: fTb (B*S*C bf16 = 2 MB) | mS (B*S*K f32 = 128 KB) | accum (2 f32)
    ushort* fTb  = (ushort*)d_ws;
    float*  mSm  = (float*)((char*)d_ws + (size_t)Bn * Sn * Cn * sizeof(ushort));
    float*  accum = mSm + (size_t)Bn * Sn * Kn;

    zero_accum_kernel<<<1, 64, 0, stream>>>(accum);
    gather_kernel<<<Bn * Sn, 256, 0, stream>>>(masks, feats, indices, fTb, mSm);
    dim3 grid(Sn / BT, Sn / BT, Bn);
    sim_kernel<<<grid, 256, 0, stream>>>(fTb, mSm, accum);
    finalize_kernel<<<1, 64, 0, stream>>>(accum, out);
}